// Round 1
// baseline (1979.798 us; speedup 1.0000x reference)
//
#include <hip/hip_runtime.h>
#include <hip/hip_bf16.h>

// Problem constants (B, C, H, W) = (8, 1024, 64, 64); N = H*W = 4096.
#define BATCH 8
#define CH    1024
#define NN    4096

typedef __attribute__((ext_vector_type(8))) short bf16x8;   // 8 bf16 = 4 VGPRs
typedef __attribute__((ext_vector_type(4))) float f32x4;

struct bhalf4 { __hip_bfloat16 x, y, z, w; };               // 8 bytes

// ---------------------------------------------------------------------------
// Transpose + cast: in [C][N] fp32  ->  out [N][C] bf16  (K-contiguous for MFMA)
// ---------------------------------------------------------------------------
__global__ __launch_bounds__(256) void transpose_cast(
    const float* __restrict__ in, __hip_bfloat16* __restrict__ out) {
  __shared__ float tile[32][33];                            // +1 pad: no bank conflicts
  int n0 = blockIdx.x * 32;
  int c0 = blockIdx.y * 32;
  int tx = threadIdx.x;   // 0..31
  int ty = threadIdx.y;   // 0..7
#pragma unroll
  for (int i = 0; i < 4; ++i) {
    int c = c0 + ty + i * 8;
    tile[ty + i * 8][tx] = in[(size_t)c * NN + n0 + tx];
  }
  __syncthreads();
#pragma unroll
  for (int i = 0; i < 4; ++i) {
    int n = n0 + ty + i * 8;
    out[(size_t)n * CH + c0 + tx] = __float2bfloat16(tile[tx][ty + i * 8]);
  }
}

// ---------------------------------------------------------------------------
// Plain cast: in [C][N] fp32 -> out [C][N] bf16 (mo is already K-contiguous)
// ---------------------------------------------------------------------------
__global__ __launch_bounds__(256) void convert_cast(
    const float4* __restrict__ in, bhalf4* __restrict__ out) {
  size_t i = (size_t)blockIdx.x * 256 + threadIdx.x;
  float4 v = in[i];
  bhalf4 o;
  o.x = __float2bfloat16(v.x);
  o.y = __float2bfloat16(v.y);
  o.z = __float2bfloat16(v.z);
  o.w = __float2bfloat16(v.w);
  out[i] = o;
}

// ---------------------------------------------------------------------------
// a_sq[n] = sum_c mk[c][n]^2  (fp32 input, atomic partials over c-chunks)
// grid (N/256, C/64)
// ---------------------------------------------------------------------------
__global__ __launch_bounds__(256) void asq_partial(
    const float* __restrict__ mk, float* __restrict__ a_sq) {
  int n = blockIdx.x * 256 + threadIdx.x;
  int c0 = blockIdx.y * 64;
  float s = 0.f;
#pragma unroll 4
  for (int c = c0; c < c0 + 64; ++c) {
    float v = mk[(size_t)c * NN + n];
    s += v * v;
  }
  atomicAdd(&a_sq[n], s);
}

// ---------------------------------------------------------------------------
// gemm_bt: A [M][K] row-major bf16, Bm [Ncols][K] row-major bf16,
//          Cm[m][n] = sum_k A[m][k] * Bm[n][k]   (fp32 out, leading dim ldc)
// 128x128 tile / block (256 threads = 4 waves, each wave 64x64),
// BK=32, mfma_f32_16x16x32_bf16, global_load_lds width=16  (m97 structure).
// ---------------------------------------------------------------------------
__global__ __launch_bounds__(256) void gemm_bt(
    const __hip_bfloat16* __restrict__ A, const __hip_bfloat16* __restrict__ Bm,
    float* __restrict__ Cm, int K, int ldc) {
  __shared__ __hip_bfloat16 As[128 * 32];   // [row][k] rows of 64B
  __shared__ __hip_bfloat16 Bs[128 * 32];

  int tid  = threadIdx.x;
  int wave = tid >> 6;
  int lane = tid & 63;
  int m0 = blockIdx.y * 128;
  int n0 = blockIdx.x * 128;

  int wm = (wave >> 1) * 64;   // wave quadrant within the 128x128 tile
  int wn = (wave & 1) * 64;

  int fl   = lane & 15;        // fragment row (A: m, B: n)
  int quad = lane >> 4;        // k-chunk: k = quad*8 + j

  f32x4 acc[4][4] = {};

  // staging geometry: chunk = 16 rows x 32 cols bf16 = 1 KiB = one wave-load
  int srow = lane >> 2;               // 0..15 within chunk
  int scol = (lane & 3) * 8;          // element offset 0,8,16,24

  for (int k0 = 0; k0 < K; k0 += 32) {
#pragma unroll
    for (int j = 0; j < 2; ++j) {
      int chunk = wave * 2 + j;                 // 0..7 (uniform per wave)
      int row = chunk * 16 + srow;              // 0..127
      const __hip_bfloat16* ga = A  + (size_t)(m0 + row) * K + k0 + scol;
      const __hip_bfloat16* gb = Bm + (size_t)(n0 + row) * K + k0 + scol;
      __builtin_amdgcn_global_load_lds(
          (const __attribute__((address_space(1))) void*)ga,
          (__attribute__((address_space(3))) void*)(As + chunk * 512), 16, 0, 0);
      __builtin_amdgcn_global_load_lds(
          (const __attribute__((address_space(1))) void*)gb,
          (__attribute__((address_space(3))) void*)(Bs + chunk * 512), 16, 0, 0);
    }
    __syncthreads();   // compiler drains vmcnt before s_barrier

    bf16x8 af[4], bfr[4];
#pragma unroll
    for (int i = 0; i < 4; ++i) {
      af[i]  = *(const bf16x8*)(As + (wm + i * 16 + fl) * 32 + quad * 8);
      bfr[i] = *(const bf16x8*)(Bs + (wn + i * 16 + fl) * 32 + quad * 8);
    }
#pragma unroll
    for (int i = 0; i < 4; ++i)
#pragma unroll
      for (int jj = 0; jj < 4; ++jj)
        acc[i][jj] = __builtin_amdgcn_mfma_f32_16x16x32_bf16(
            af[i], bfr[jj], acc[i][jj], 0, 0, 0);
    __syncthreads();
  }

  // C/D layout (verified m89/m91): col = lane&15, row = quad*4 + reg
#pragma unroll
  for (int i = 0; i < 4; ++i)
#pragma unroll
    for (int jj = 0; jj < 4; ++jj) {
      int col = n0 + wn + jj * 16 + fl;
#pragma unroll
      for (int r = 0; r < 4; ++r) {
        int row = m0 + wm + i * 16 + quad * 4 + r;
        Cm[(size_t)row * ldc + col] = acc[i][jj][r];
      }
    }
}

// ---------------------------------------------------------------------------
// Row softmax: logits t[n] = 2*S[m][n] - a_sq[n], softmax over n with /32 scale,
// write normalized probs as bf16. One block (256 thr) per row m; 16 elems/thread.
// ---------------------------------------------------------------------------
__device__ __forceinline__ float wave_max_f(float v) {
#pragma unroll
  for (int off = 32; off > 0; off >>= 1) v = fmaxf(v, __shfl_xor(v, off));
  return v;
}
__device__ __forceinline__ float wave_sum_f(float v) {
#pragma unroll
  for (int off = 32; off > 0; off >>= 1) v += __shfl_xor(v, off);
  return v;
}

__global__ __launch_bounds__(256) void softmax_rows(
    const float* __restrict__ S, const float* __restrict__ a_sq,
    __hip_bfloat16* __restrict__ P) {
  int m = blockIdx.x;
  int tid = threadIdx.x;
  int lane = tid & 63, wave = tid >> 6;
  const float* row = S + (size_t)m * NN;

  float t[16];
  float lmax = -1e30f;
#pragma unroll
  for (int i = 0; i < 16; ++i) {
    int n = tid + i * 256;
    float v = 2.f * row[n] - a_sq[n];
    t[i] = v;
    lmax = fmaxf(lmax, v);
  }
  __shared__ float redm[4], reds[4];
  float wm = wave_max_f(lmax);
  if (lane == 0) redm[wave] = wm;
  __syncthreads();
  lmax = fmaxf(fmaxf(redm[0], redm[1]), fmaxf(redm[2], redm[3]));

  float e[16];
  float lsum = 0.f;
#pragma unroll
  for (int i = 0; i < 16; ++i) {
    e[i] = __expf((t[i] - lmax) * 0.03125f);   // /sqrt(1024) = /32
    lsum += e[i];
  }
  float ws = wave_sum_f(lsum);
  if (lane == 0) reds[wave] = ws;
  __syncthreads();
  lsum = reds[0] + reds[1] + reds[2] + reds[3];
  float inv = 1.f / lsum;

  __hip_bfloat16* prow = P + (size_t)m * NN;
#pragma unroll
  for (int i = 0; i < 16; ++i)
    prow[tid + i * 256] = __float2bfloat16(e[i] * inv);
}

// ---------------------------------------------------------------------------
// Copy curr_value into the second half of each batch's output channel block.
// ---------------------------------------------------------------------------
__global__ __launch_bounds__(256) void copy_curr(
    const float4* __restrict__ src, float4* __restrict__ dst) {
  size_t idx = (size_t)blockIdx.x * 256 + threadIdx.x;   // 0 .. 8*1024*4096/4-1
  size_t b = idx >> 20;                                  // / (1024*4096/4)
  size_t r = idx & 1048575;
  dst[b * 2097152 + 1048576 + r] = src[idx];
}

// ---------------------------------------------------------------------------
extern "C" void kernel_launch(void* const* d_in, const int* in_sizes, int n_in,
                              void* d_out, int out_size, void* d_ws, size_t ws_size,
                              hipStream_t stream) {
  const float* prev_key   = (const float*)d_in[0];
  const float* prev_value = (const float*)d_in[1];
  const float* curr_key   = (const float*)d_in[2];
  const float* curr_value = (const float*)d_in[3];
  float* out = (float*)d_out;

  char* ws = (char*)d_ws;
  __hip_bfloat16* mk_t = (__hip_bfloat16*)(ws);                    //  8 MB [N][C]
  __hip_bfloat16* qk_t = (__hip_bfloat16*)(ws + (8u << 20));       //  8 MB [N][C]
  __hip_bfloat16* mo_b = (__hip_bfloat16*)(ws + (16u << 20));      //  8 MB [C][N]
  float*          a_sq = (float*)(ws + (24u << 20));               // 16 KB
  float*          S    = (float*)(ws + (32u << 20));               // 64 MB [N][N]
  __hip_bfloat16* P    = (__hip_bfloat16*)(ws + (96u << 20));      // 32 MB [N][N]

  for (int b = 0; b < BATCH; ++b) {
    const size_t boff = (size_t)b * CH * NN;
    const float* mk = prev_key + boff;
    const float* qk = curr_key + boff;
    const float* mo = prev_value + boff;
    float* outb = out + (size_t)b * 2 * CH * NN;

    transpose_cast<<<dim3(NN / 32, CH / 32), dim3(32, 8), 0, stream>>>(mk, mk_t);
    transpose_cast<<<dim3(NN / 32, CH / 32), dim3(32, 8), 0, stream>>>(qk, qk_t);
    convert_cast<<<CH * NN / 4 / 256, 256, 0, stream>>>(
        (const float4*)mo, (bhalf4*)mo_b);
    hipMemsetAsync(a_sq, 0, NN * sizeof(float), stream);
    asq_partial<<<dim3(NN / 256, CH / 64), 256, 0, stream>>>(mk, a_sq);

    // S[m][n] = sum_c qk_t[m][c] * mk_t[n][c]   (= ab[n,m])
    gemm_bt<<<dim3(NN / 128, NN / 128), 256, 0, stream>>>(qk_t, mk_t, S, CH, NN);

    softmax_rows<<<NN, 256, 0, stream>>>(S, a_sq, P);

    // mem[c][m] = sum_n mo_b[c][n] * P[m][n]  -> first half of outb
    gemm_bt<<<dim3(NN / 128, CH / 128), 256, 0, stream>>>(mo_b, P, outb, NN, NN);
  }

  copy_curr<<<BATCH * CH * NN / 4 / 256, 256, 0, stream>>>(
      (const float4*)curr_value, (float4*)out);
}

// Round 2
// 1671.322 us; speedup vs baseline: 1.1846x; 1.1846x over previous
//
#include <hip/hip_runtime.h>
#include <hip/hip_bf16.h>

// Problem constants (B, C, H, W) = (8, 1024, 64, 64); N = H*W = 4096.
#define BATCH 8
#define CH    1024
#define NN    4096

typedef __attribute__((ext_vector_type(8))) short bf16x8;   // 8 bf16 = 4 VGPRs
typedef __attribute__((ext_vector_type(4))) float f32x4;

struct bhalf4 { __hip_bfloat16 x, y, z, w; };               // 8 bytes

// ---------------------------------------------------------------------------
// Transpose + cast, batched over z: in [B][C][N] fp32 -> out [B][N][C] bf16.
// ASQ variant also accumulates a_sq[b][n] = sum_c in[b][c][n]^2 (fp32).
// ---------------------------------------------------------------------------
template <bool ASQ>
__global__ __launch_bounds__(256) void transpose_cast_b(
    const float* __restrict__ in_all, __hip_bfloat16* __restrict__ out_all,
    float* __restrict__ asq_all) {
  int bz = blockIdx.z;
  const float* in = in_all + (size_t)bz * CH * NN;
  __hip_bfloat16* out = out_all + (size_t)bz * NN * CH;

  __shared__ float tile[32][33];                            // +1 pad: no bank conflicts
  int n0 = blockIdx.x * 32;
  int c0 = blockIdx.y * 32;
  int tx = threadIdx.x;   // 0..31
  int ty = threadIdx.y;   // 0..7

  float sq = 0.f;
#pragma unroll
  for (int i = 0; i < 4; ++i) {
    int c = c0 + ty + i * 8;
    float v = in[(size_t)c * NN + n0 + tx];
    tile[ty + i * 8][tx] = v;
    if (ASQ) sq += v * v;
  }
  if (ASQ) atomicAdd(&asq_all[(size_t)bz * NN + n0 + tx], sq);
  __syncthreads();
#pragma unroll
  for (int i = 0; i < 4; ++i) {
    int n = n0 + ty + i * 8;
    out[(size_t)n * CH + c0 + tx] = __float2bfloat16(tile[tx][ty + i * 8]);
  }
}

// ---------------------------------------------------------------------------
// Plain cast: [B*C*N] fp32 -> bf16 flat (mo is already K-contiguous).
// ---------------------------------------------------------------------------
__global__ __launch_bounds__(256) void convert_cast(
    const float4* __restrict__ in, bhalf4* __restrict__ out) {
  size_t i = (size_t)blockIdx.x * 256 + threadIdx.x;
  float4 v = in[i];
  bhalf4 o;
  o.x = __float2bfloat16(v.x);
  o.y = __float2bfloat16(v.y);
  o.z = __float2bfloat16(v.z);
  o.w = __float2bfloat16(v.w);
  out[i] = o;
}

// ---------------------------------------------------------------------------
// GEMM1 + fused exp epilogue (no max-subtraction; logits/32 bounded ~[-70,41]).
//   ab[m][n] = sum_c qk_t[m][c] * mk_t[n][c]     (bf16 MFMA, fp32 acc)
//   e = exp((2*ab - asq[n]) / 32)  ->  P[m][n] bf16 (unnormalized)
//   rowsum[m] += partial sums of e  (device atomics)
// 128x128 tile, 4 waves each 64x64, BK=32, global_load_lds width 16 (m97).
// Grid (N/128, N/128, B).
// ---------------------------------------------------------------------------
__global__ __launch_bounds__(256) void gemm1_exp(
    const __hip_bfloat16* __restrict__ Aall, const __hip_bfloat16* __restrict__ Ball,
    __hip_bfloat16* __restrict__ Pall, const float* __restrict__ asq_all,
    float* __restrict__ rowsum_all) {
  int bz = blockIdx.z;
  const __hip_bfloat16* A  = Aall + (size_t)bz * NN * CH;
  const __hip_bfloat16* Bm = Ball + (size_t)bz * NN * CH;
  __hip_bfloat16* P        = Pall + (size_t)bz * NN * NN;
  const float* asq         = asq_all + (size_t)bz * NN;
  float* rowsum            = rowsum_all + (size_t)bz * NN;

  __shared__ __hip_bfloat16 As[128 * 32];
  __shared__ __hip_bfloat16 Bs[128 * 32];

  int tid  = threadIdx.x;
  int wave = tid >> 6;
  int lane = tid & 63;
  int m0 = blockIdx.y * 128;
  int n0 = blockIdx.x * 128;
  int wm = (wave >> 1) * 64;
  int wn = (wave & 1) * 64;
  int fl   = lane & 15;
  int quad = lane >> 4;

  f32x4 acc[4][4] = {};

  int srow = lane >> 2;
  int scol = (lane & 3) * 8;

  for (int k0 = 0; k0 < CH; k0 += 32) {
#pragma unroll
    for (int j = 0; j < 2; ++j) {
      int chunk = wave * 2 + j;
      int row = chunk * 16 + srow;
      const __hip_bfloat16* ga = A  + (size_t)(m0 + row) * CH + k0 + scol;
      const __hip_bfloat16* gb = Bm + (size_t)(n0 + row) * CH + k0 + scol;
      __builtin_amdgcn_global_load_lds(
          (const __attribute__((address_space(1))) void*)ga,
          (__attribute__((address_space(3))) void*)(As + chunk * 512), 16, 0, 0);
      __builtin_amdgcn_global_load_lds(
          (const __attribute__((address_space(1))) void*)gb,
          (__attribute__((address_space(3))) void*)(Bs + chunk * 512), 16, 0, 0);
    }
    __syncthreads();

    bf16x8 af[4], bfr[4];
#pragma unroll
    for (int i = 0; i < 4; ++i) {
      af[i]  = *(const bf16x8*)(As + (wm + i * 16 + fl) * 32 + quad * 8);
      bfr[i] = *(const bf16x8*)(Bs + (wn + i * 16 + fl) * 32 + quad * 8);
    }
#pragma unroll
    for (int i = 0; i < 4; ++i)
#pragma unroll
      for (int jj = 0; jj < 4; ++jj)
        acc[i][jj] = __builtin_amdgcn_mfma_f32_16x16x32_bf16(
            af[i], bfr[jj], acc[i][jj], 0, 0, 0);
    __syncthreads();
  }

  // Epilogue: e = exp((2*ab - asq[n])*(1/32)); write bf16 P; row partial sums.
  // C/D layout: col = lane&15 (+jj*16), row = quad*4 + reg (+i*16).
  float rs[4][4] = {{0.f}};   // [i][r] partial sums over this lane's 4 cols
#pragma unroll
  for (int jj = 0; jj < 4; ++jj) {
    int col = n0 + wn + jj * 16 + fl;
    float aq = asq[col];
#pragma unroll
    for (int i = 0; i < 4; ++i) {
#pragma unroll
      for (int r = 0; r < 4; ++r) {
        int row = m0 + wm + i * 16 + quad * 4 + r;
        float e = __expf((2.f * acc[i][jj][r] - aq) * 0.03125f);
        P[(size_t)row * NN + col] = __float2bfloat16(e);
        rs[i][r] += e;
      }
    }
  }
  // Reduce across the 16 lanes (fl) that share the same row set.
#pragma unroll
  for (int i = 0; i < 4; ++i)
#pragma unroll
    for (int r = 0; r < 4; ++r) {
#pragma unroll
      for (int off = 1; off < 16; off <<= 1)
        rs[i][r] += __shfl_xor(rs[i][r], off);
      if (fl == 0) {
        int row = m0 + wm + i * 16 + quad * 4 + r;
        atomicAdd(&rowsum[row], rs[i][r]);
      }
    }
}

// ---------------------------------------------------------------------------
// GEMM2 with fused softmax normalization:
//   mem[c][m] = (sum_n mo[c][n] * P[m][n]) / rowsum[m]   -> out first half
// A = mo_b [C][N] bf16, Bm = P [m][n] bf16. Grid (N/128, C/128, B).
// ---------------------------------------------------------------------------
__global__ __launch_bounds__(256) void gemm2_scaled(
    const __hip_bfloat16* __restrict__ Aall, const __hip_bfloat16* __restrict__ Pall,
    float* __restrict__ out, const float* __restrict__ rowsum_all) {
  int bz = blockIdx.z;
  const __hip_bfloat16* A  = Aall + (size_t)bz * CH * NN;
  const __hip_bfloat16* Bm = Pall + (size_t)bz * NN * NN;
  float* Co                = out + (size_t)bz * 2 * CH * NN;   // first CV block
  const float* rowsum      = rowsum_all + (size_t)bz * NN;

  __shared__ __hip_bfloat16 As[128 * 32];
  __shared__ __hip_bfloat16 Bs[128 * 32];

  int tid  = threadIdx.x;
  int wave = tid >> 6;
  int lane = tid & 63;
  int m0 = blockIdx.y * 128;      // channel rows
  int n0 = blockIdx.x * 128;      // query cols
  int wm = (wave >> 1) * 64;
  int wn = (wave & 1) * 64;
  int fl   = lane & 15;
  int quad = lane >> 4;

  f32x4 acc[4][4] = {};

  int srow = lane >> 2;
  int scol = (lane & 3) * 8;

  for (int k0 = 0; k0 < NN; k0 += 32) {
#pragma unroll
    for (int j = 0; j < 2; ++j) {
      int chunk = wave * 2 + j;
      int row = chunk * 16 + srow;
      const __hip_bfloat16* ga = A  + (size_t)(m0 + row) * NN + k0 + scol;
      const __hip_bfloat16* gb = Bm + (size_t)(n0 + row) * NN + k0 + scol;
      __builtin_amdgcn_global_load_lds(
          (const __attribute__((address_space(1))) void*)ga,
          (__attribute__((address_space(3))) void*)(As + chunk * 512), 16, 0, 0);
      __builtin_amdgcn_global_load_lds(
          (const __attribute__((address_space(1))) void*)gb,
          (__attribute__((address_space(3))) void*)(Bs + chunk * 512), 16, 0, 0);
    }
    __syncthreads();

    bf16x8 af[4], bfr[4];
#pragma unroll
    for (int i = 0; i < 4; ++i) {
      af[i]  = *(const bf16x8*)(As + (wm + i * 16 + fl) * 32 + quad * 8);
      bfr[i] = *(const bf16x8*)(Bs + (wn + i * 16 + fl) * 32 + quad * 8);
    }
#pragma unroll
    for (int i = 0; i < 4; ++i)
#pragma unroll
      for (int jj = 0; jj < 4; ++jj)
        acc[i][jj] = __builtin_amdgcn_mfma_f32_16x16x32_bf16(
            af[i], bfr[jj], acc[i][jj], 0, 0, 0);
    __syncthreads();
  }

#pragma unroll
  for (int jj = 0; jj < 4; ++jj) {
    int col = n0 + wn + jj * 16 + fl;
    float inv = 1.f / rowsum[col];
#pragma unroll
    for (int i = 0; i < 4; ++i) {
#pragma unroll
      for (int r = 0; r < 4; ++r) {
        int row = m0 + wm + i * 16 + quad * 4 + r;
        Co[(size_t)row * NN + col] = acc[i][jj][r] * inv;
      }
    }
  }
}

// ---------------------------------------------------------------------------
// Copy curr_value into the second half of each batch's output channel block.
// ---------------------------------------------------------------------------
__global__ __launch_bounds__(256) void copy_curr(
    const float4* __restrict__ src, float4* __restrict__ dst) {
  size_t idx = (size_t)blockIdx.x * 256 + threadIdx.x;
  size_t b = idx >> 20;                                  // / (1024*4096/4)
  size_t r = idx & 1048575;
  dst[b * 2097152 + 1048576 + r] = src[idx];
}

// ---------------------------------------------------------------------------
extern "C" void kernel_launch(void* const* d_in, const int* in_sizes, int n_in,
                              void* d_out, int out_size, void* d_ws, size_t ws_size,
                              hipStream_t stream) {
  const float* prev_key   = (const float*)d_in[0];
  const float* prev_value = (const float*)d_in[1];
  const float* curr_key   = (const float*)d_in[2];
  const float* curr_value = (const float*)d_in[3];
  float* out = (float*)d_out;

  char* ws = (char*)d_ws;
  // Layout (ws_size ~1 GiB per harness fill): total used = 448.25 MB
  __hip_bfloat16* P    = (__hip_bfloat16*)(ws);                        // 256 MB [B][N][N]
  __hip_bfloat16* mk_t = (__hip_bfloat16*)(ws + 268435456u);           //  64 MB [B][N][C]
  __hip_bfloat16* qk_t = (__hip_bfloat16*)(ws + 335544320u);           //  64 MB [B][N][C]
  __hip_bfloat16* mo_b = (__hip_bfloat16*)(ws + 402653184u);           //  64 MB [B][C][N]
  float*          a_sq = (float*)(ws + 469762048u);                    // 128 KB [B][N]
  float*          rsum = a_sq + (size_t)BATCH * NN;                    // 128 KB [B][N]

  // Zero a_sq + rowsum (contiguous 256 KB).
  hipMemsetAsync(a_sq, 0, 2ull * BATCH * NN * sizeof(float), stream);

  transpose_cast_b<true><<<dim3(NN / 32, CH / 32, BATCH), dim3(32, 8), 0, stream>>>(
      prev_key, mk_t, a_sq);
  transpose_cast_b<false><<<dim3(NN / 32, CH / 32, BATCH), dim3(32, 8), 0, stream>>>(
      curr_key, qk_t, nullptr);
  convert_cast<<<(size_t)BATCH * CH * NN / 4 / 256, 256, 0, stream>>>(
      (const float4*)prev_value, (bhalf4*)mo_b);

  gemm1_exp<<<dim3(NN / 128, NN / 128, BATCH), 256, 0, stream>>>(
      qk_t, mk_t, P, a_sq, rsum);

  gemm2_scaled<<<dim3(NN / 128, CH / 128, BATCH), 256, 0, stream>>>(
      mo_b, P, out, rsum);

  copy_curr<<<(size_t)BATCH * CH * NN / 4 / 256, 256, 0, stream>>>(
      (const float4*)curr_value, (float4*)out);
}